// Round 7
// baseline (651.965 us; speedup 1.0000x reference)
//
#include <hip/hip_runtime.h>
#include <cstdint>

#define B_ 16
#define H_ 224
#define W_ 224
#define C_ 32
#define HW_ (H_*W_)            // 50176

__device__ __forceinline__ unsigned int enc_f32(float f) {
    unsigned int u = __float_as_uint(f);
    return (u & 0x80000000u) ? ~u : (u | 0x80000000u);
}
__device__ __forceinline__ float dec_f32(unsigned int u) {
    unsigned int v = (u & 0x80000000u) ? (u & 0x7fffffffu) : ~u;
    return __uint_as_float(v);
}

__global__ void k_init(unsigned int* scratch) {
    int t = threadIdx.x;
    if (t < B_) { scratch[t] = 0xFFFFFFFFu; scratch[B_ + t] = 0u; }
}

// K1 v2: pure streaming per-sample min/max over NHWC x (no transpose).
__global__ __launch_bounds__(256) void k_minmax(
        const float* __restrict__ x, unsigned int* __restrict__ scratch) {
    __shared__ float rmin[4], rmax[4];
    int t = threadIdx.x;
    int b = blockIdx.y;
    const float4* p = (const float4*)(x + (size_t)b * HW_ * C_);
    const int n4 = HW_ * C_ / 4;   // 401408
    float vmin = 1e30f, vmax = -1e30f;
    for (int i = blockIdx.x * 256 + t; i < n4; i += gridDim.x * 256) {
        float4 v = p[i];
        vmin = fminf(vmin, fminf(fminf(v.x, v.y), fminf(v.z, v.w)));
        vmax = fmaxf(vmax, fmaxf(fmaxf(v.x, v.y), fmaxf(v.z, v.w)));
    }
    for (int off = 32; off; off >>= 1) {
        vmin = fminf(vmin, __shfl_down(vmin, off));
        vmax = fmaxf(vmax, __shfl_down(vmax, off));
    }
    if ((t & 63) == 0) { rmin[t >> 6] = vmin; rmax[t >> 6] = vmax; }
    __syncthreads();
    if (t == 0) {
        atomicMin(&scratch[b],      enc_f32(fminf(fminf(rmin[0], rmin[1]), fminf(rmin[2], rmin[3]))));
        atomicMax(&scratch[B_ + b], enc_f32(fmaxf(fmaxf(rmax[0], rmax[1]), fmaxf(rmax[2], rmax[3]))));
    }
}

// K2 v7: v6 with 2 co-resident blocks/CU.
// R6 counters: WRITE now ideal (105MB, XCD pairing confirmed), FETCH 70MB
// (L3-resident after k_minmax), BW 27% peak, VALUBusy 34%, Occ 41% -- the
// ~55% residual is barrier drain at 1 block/CU (nothing to overlap).
// Change: H split into 8 chunks of 28 rows -> grid 512 blocks = 2/CU
// (LDS 63KB x2 = 126KB <= 160KB; launch_bounds(1024,8) pins VGPR<=64 --
// body used exactly 64 in R5/R6). Warmup cost 44 vs 72 steps per 28 vs 56
// rows = 1.22x issue work, bought back by overlap. Ring phases are
// it-relative (h0 never enters slot math), so h0=28k is safe; the 44-step
// schedule is 5x8 steps + explicit 2-epoch tail so &7/&3 stay literal.
// XCD write pairing now bid/bid+256 (256%8==0 -> same XCD).
__global__ __launch_bounds__(1024, 8) void k_fused(
        const float* __restrict__ x, float* __restrict__ out,
        const float* __restrict__ gamma, const float* __restrict__ beta,
        const float* __restrict__ mmean, const float* __restrict__ mvar,
        const unsigned int* __restrict__ scratch) {
    __shared__ float lin[4][16][130];
    __shared__ float lout[4][16][116];
    const int t    = threadIdx.x;
    const int wid  = t >> 6;               // 0..15: channel within group
    const int lane = t & 63;

    int bid   = blockIdx.x;                // cg*256 + ((b*8+chunk)*2+strip)
    int cg    = bid >> 8;                  // pair blocks p, p+256: same XCD
    int r     = bid & 255;
    int strip = r & 1;
    int chunk = (r >> 1) & 7;              // 0..7
    int b     = r >> 4;

    const int cbase = cg * 16;
    const int c     = cbase + wid;         // this wave's channel
    const int h0    = chunk * 28;          // 0,28,...,196
    const int sbase = strip * 112;

    // BN constants (wave-uniform)
    float sc = gamma[c] * rsqrtf(mvar[c] + 1e-3f);
    float bi = beta[c] - mmean[c] * sc;

    float mn   = dec_f32(scratch[b]);
    float mx   = dec_f32(scratch[B_ + b]);
    float inv  = 1.0f / (mx - mn + 1e-7f);
    float minv = mn * inv;

    // pipeline-lane column mapping
    int c0 = sbase - 8 + 2 * lane;
    int c1 = c0 + 1;
    bool mC = (c0 >= 0) && (c0 <= W_ - 2);
    bool laneok = (lane >= 4) && (lane <= 59);

    // loader/storer mapping: 8 threads per pixel cover a 64B half-line
    int col_l = t >> 3;                    // 0..127
    int lch   = (t & 7) * 2;               // 0,2,...,14
    int wld   = min(max(sbase - 8 + col_l, 0), W_ - 1);
    int wst   = sbase - 8 + col_l;         // valid when colok
    int cs    = col_l - 8;                 // lout col index, valid when colok
    bool colok = (col_l >= 8) && (col_l < 120);
    const float* xb = x   + (size_t)b * HW_ * C_ + cbase + lch;
    float*       ob = out + (size_t)b * HW_ * C_ + cbase + lch;

    // per-column W-direction valid counts and folded constants
    float cw2_0  = (float)(min(c0+1, W_-1) - c0 + 1);
    float cw2_1  = (float)(min(c1+1, W_-1) - c1 + 1);
    float cw4_0  = (float)(min(c0+2, W_-1) - max(c0-1, 0) + 1);
    float cw4_1  = (float)(min(c1+2, W_-1) - max(c1-1, 0) + 1);
    float cw8_0  = (float)(min(c0+4, W_-1) - max(c0-3, 0) + 1);
    float cw8_1  = (float)(min(c1+4, W_-1) - max(c1-3, 0) + 1);
    float cw16_0 = (float)(min(c0+8, W_-1) - max(c0-7, 0) + 1);
    float cw16_1 = (float)(min(c1+8, W_-1) - max(c1-7, 0) + 1);
    float e2_0  = minv * cw2_0,  e2_1  = minv * cw2_1;
    float e4_0  = minv * cw4_0,  e4_1  = minv * cw4_1;
    float e8_0  = minv * cw8_0,  e8_1  = minv * cw8_1;
    float e16_0 = minv * cw16_0, e16_1 = minv * cw16_1;
    float d2_0  = 1e-7f -  2.0f * e2_0,  d2_1  = 1e-7f -  2.0f * e2_1;
    float d4_0  = 1e-7f -  4.0f * e4_0,  d4_1  = 1e-7f -  4.0f * e4_1;
    float d8_0  = 1e-7f -  8.0f * e8_0,  d8_1  = 1e-7f -  8.0f * e8_1;
    float d16_0 = 1e-7f - 16.0f * e16_0, d16_1 = 1e-7f - 16.0f * e16_1;

    float hp0 = 0.f, hp1 = 0.f;            // Xh[a-1]
    float rB4[2][2]  = {};                 // delay-2
    float rB8[2][4]  = {};                 // delay-4
    float rB16[2][8] = {};                 // delay-8
    float acc[2][8]  = {};                 // alpha partials, slot = step & 7

#define LDROW(AR) (*(const float2*)(xb + (size_t)((min(max((AR), 0), H_-1)) * W_ + wld) * C_))

// one pipeline step: read row for step U_ from lin[U_&3], update rings,
// emit out-row into lout[U_&3]. U_ literal; IT_/A_ wave-uniform runtime.
#define STEP(U_, IT_, A_) do {                                               \
    float2 lv = *(const float2*)&lin[(U_)&3][wid][2*lane];                   \
    bool rowok = ((A_) >= 0) && ((A_) < H_);                                 \
    float x0 = (rowok && mC) ? lv.x : 0.f;                                   \
    float x1 = (rowok && mC) ? lv.y : 0.f;                                   \
    float nx0 = __shfl_down(x0, 1);                                          \
    float xh0 = x0 + x1;                                                     \
    float xh1 = x1 + nx0;                                                    \
    float g2_0 = hp0 + xh0; hp0 = xh0;                                       \
    float g2_1 = hp1 + xh1; hp1 = xh1;                                       \
    float b4n_0 = g2_0 + __shfl_down(g2_0, 1);                               \
    float b4n_1 = g2_1 + __shfl_down(g2_1, 1);                               \
    float a4_0 = rB4[0][(U_)&1] + b4n_0; rB4[0][(U_)&1] = b4n_0;             \
    float a4_1 = rB4[1][(U_)&1] + b4n_1; rB4[1][(U_)&1] = b4n_1;             \
    float b8n_0 = a4_0 + __shfl_down(a4_0, 2);                               \
    float b8n_1 = a4_1 + __shfl_down(a4_1, 2);                               \
    float a8_0 = rB8[0][(U_)&3] + b8n_0; rB8[0][(U_)&3] = b8n_0;             \
    float a8_1 = rB8[1][(U_)&3] + b8n_1; rB8[1][(U_)&3] = b8n_1;             \
    float b16n_0 = a8_0 + __shfl_down(a8_0, 4);                              \
    float b16n_1 = a8_1 + __shfl_down(a8_1, 4);                              \
    float a16_0 = rB16[0][(U_)&7] + b16n_0; rB16[0][(U_)&7] = b16n_0;        \
    float a16_1 = rB16[1][(U_)&7] + b16n_1; rB16[1][(U_)&7] = b16n_1;        \
    float g4_0  = __shfl_up(a4_1, 1);                                        \
    float g4_1  = a4_0;                                                      \
    float g8_0  = __shfl_up(a8_1, 2);                                        \
    float g8_1  = __shfl_up(a8_0, 1);                                        \
    float g16_0 = __shfl_up(a16_1, 4);                                       \
    float g16_1 = __shfl_up(a16_0, 3);                                       \
    float l1_0, l1_1, l2_0, l2_1, l3_0, l3_1, l4_0, l4_1;                    \
    if ((A_) >= 15 && (A_) <= 223) {                                         \
        l1_0 = __log2f(fmaxf(fmaf(g2_0,  inv, d2_0 ), 1e-7f));               \
        l1_1 = __log2f(fmaxf(fmaf(g2_1,  inv, d2_1 ), 1e-7f));               \
        l2_0 = __log2f(fmaxf(fmaf(g4_0,  inv, d4_0 ), 1e-7f));               \
        l2_1 = __log2f(fmaxf(fmaf(g4_1,  inv, d4_1 ), 1e-7f));               \
        l3_0 = __log2f(fmaxf(fmaf(g8_0,  inv, d8_0 ), 1e-7f));               \
        l3_1 = __log2f(fmaxf(fmaf(g8_1,  inv, d8_1 ), 1e-7f));               \
        l4_0 = __log2f(fmaxf(fmaf(g16_0, inv, d16_0), 1e-7f));               \
        l4_1 = __log2f(fmaxf(fmaf(g16_1, inv, d16_1), 1e-7f));               \
    } else {                                                                 \
        int o1 = (A_) - 1, o2 = (A_) - 2, o3 = (A_) - 4, o4 = (A_) - 8;      \
        float ch2  = (float)(min(o1+1, H_-1) - o1 + 1);                      \
        float ch4  = (float)(min(o2+2, H_-1) - max(o2-1, 0) + 1);            \
        float ch8  = (float)(min(o3+4, H_-1) - max(o3-3, 0) + 1);            \
        float ch16 = (float)(min(o4+8, H_-1) - max(o4-7, 0) + 1);            \
        l1_0 = __log2f(fmaxf(fmaf(-e2_0,  ch2,  fmaf(g2_0,  inv, 1e-7f)), 1e-7f)); \
        l1_1 = __log2f(fmaxf(fmaf(-e2_1,  ch2,  fmaf(g2_1,  inv, 1e-7f)), 1e-7f)); \
        l2_0 = __log2f(fmaxf(fmaf(-e4_0,  ch4,  fmaf(g4_0,  inv, 1e-7f)), 1e-7f)); \
        l2_1 = __log2f(fmaxf(fmaf(-e4_1,  ch4,  fmaf(g4_1,  inv, 1e-7f)), 1e-7f)); \
        l3_0 = __log2f(fmaxf(fmaf(-e8_0,  ch8,  fmaf(g8_0,  inv, 1e-7f)), 1e-7f)); \
        l3_1 = __log2f(fmaxf(fmaf(-e8_1,  ch8,  fmaf(g8_1,  inv, 1e-7f)), 1e-7f)); \
        l4_0 = __log2f(fmaxf(fmaf(-e16_0, ch16, fmaf(g16_0, inv, 1e-7f)), 1e-7f)); \
        l4_1 = __log2f(fmaxf(fmaf(-e16_1, ch16, fmaf(g16_1, inv, 1e-7f)), 1e-7f)); \
    }                                                                        \
    acc[0][(U_)&7] = -0.3f * l1_0;                                           \
    acc[1][(U_)&7] = -0.3f * l1_1;                                           \
    acc[0][((U_)+7)&7] = fmaf(-0.1f, l2_0, acc[0][((U_)+7)&7]);              \
    acc[1][((U_)+7)&7] = fmaf(-0.1f, l2_1, acc[1][((U_)+7)&7]);              \
    acc[0][((U_)+5)&7] = fmaf( 0.1f, l3_0, acc[0][((U_)+5)&7]);              \
    acc[1][((U_)+5)&7] = fmaf( 0.1f, l3_1, acc[1][((U_)+5)&7]);              \
    if ((IT_) >= 15 && (IT_) <= 42) {                                        \
        float al0 = fmaf(0.3f, l4_0, acc[0][((U_)+1)&7]);                    \
        float al1 = fmaf(0.3f, l4_1, acc[1][((U_)+1)&7]);                    \
        if (laneok) {                                                        \
            float2 ev;                                                       \
            ev.x = fmaf(sc, al0, bi);                                        \
            ev.y = fmaf(sc, al1, bi);                                        \
            *(float2*)&lout[(U_)&3][wid][2*lane - 8] = ev;                   \
        }                                                                    \
    }                                                                        \
} while (0)

// one epoch = 2 steps (IT_ even, U0_ = IT_&7 literal):
// barrier; store rows emitted last epoch; stage rows for steps IT_+2/+3;
// issue loads for IT_+4/+5; run STEP(IT_), STEP(IT_+1).
#define EPOCH(U0_, IT_) do {                                                 \
    int a_ = h0 - 7 + (IT_);                                                 \
    __syncthreads();                                                         \
    if ((IT_) >= 17 && colok) {                                              \
        int o = h0 - 17 + (IT_);                                             \
        float2 sv;                                                           \
        sv.x = lout[((U0_)+2)&3][lch][cs];                                   \
        sv.y = lout[((U0_)+2)&3][lch + 1][cs];                               \
        *(float2*)(ob + (size_t)(o * W_ + wst) * C_) = sv;                   \
    }                                                                        \
    if ((IT_) >= 16 && colok) {                                              \
        int o = h0 - 16 + (IT_);                                             \
        float2 sv;                                                           \
        sv.x = lout[((U0_)+3)&3][lch][cs];                                   \
        sv.y = lout[((U0_)+3)&3][lch + 1][cs];                               \
        *(float2*)(ob + (size_t)(o * W_ + wst) * C_) = sv;                   \
    }                                                                        \
    lin[((U0_)+2)&3][lch][col_l]     = q0.x;                                 \
    lin[((U0_)+2)&3][lch + 1][col_l] = q0.y;                                 \
    lin[((U0_)+3)&3][lch][col_l]     = q1.x;                                 \
    lin[((U0_)+3)&3][lch + 1][col_l] = q1.y;                                 \
    q0 = LDROW(a_ + 4);                                                      \
    q1 = LDROW(a_ + 5);                                                      \
    STEP((U0_),     (IT_),     a_);                                          \
    STEP((U0_) + 1, (IT_) + 1, a_ + 1);                                      \
} while (0)

    // prologue: rows for steps 0,1 into lin[0],lin[1]; q0,q1 = rows for 2,3
    float2 q0, q1;
    {
        float2 r0 = LDROW(h0 - 7);
        lin[0][lch][col_l] = r0.x; lin[0][lch + 1][col_l] = r0.y;
        float2 r1 = LDROW(h0 - 6);
        lin[1][lch][col_l] = r1.x; lin[1][lch + 1][col_l] = r1.y;
        q0 = LDROW(h0 - 5);
        q1 = LDROW(h0 - 4);
    }

    // 44 steps = 22 epochs: 5 groups of 4 epochs + explicit 2-epoch tail
    for (int g = 0; g < 5; ++g) {
        int it0 = g * 8;
        EPOCH(0, it0);
        EPOCH(2, it0 + 2);
        EPOCH(4, it0 + 4);
        EPOCH(6, it0 + 6);
    }
    EPOCH(0, 40);
    EPOCH(2, 42);

    // epilogue: row emitted at step 42 (buffer 42&3 = 2), o = h0+27
    __syncthreads();
    if (colok) {
        float2 sv;
        sv.x = lout[2][lch][cs];
        sv.y = lout[2][lch + 1][cs];
        *(float2*)(ob + (size_t)((h0 + 27) * W_ + wst) * C_) = sv;
    }
#undef EPOCH
#undef STEP
#undef LDROW
}

extern "C" void kernel_launch(void* const* d_in, const int* in_sizes, int n_in,
                              void* d_out, int out_size, void* d_ws, size_t ws_size,
                              hipStream_t stream) {
    const float* x     = (const float*)d_in[0];
    const float* gamma = (const float*)d_in[1];
    const float* beta  = (const float*)d_in[2];
    const float* mmean = (const float*)d_in[3];
    const float* mvar  = (const float*)d_in[4];
    float* out = (float*)d_out;

    unsigned int* scratch = (unsigned int*)d_ws;  // 32 uints

    k_init<<<1, 64, 0, stream>>>(scratch);
    k_minmax<<<dim3(128, B_), 256, 0, stream>>>(x, scratch);
    k_fused<<<512, 1024, 0, stream>>>(x, out, gamma, beta, mmean, mvar, scratch);
}

// Round 8
// 315.174 us; speedup vs baseline: 2.0686x; 2.0686x over previous
//
#include <hip/hip_runtime.h>
#include <cstdint>

#define B_ 16
#define H_ 224
#define W_ 224
#define C_ 32
#define HW_ (H_*W_)            // 50176

__device__ __forceinline__ unsigned int enc_f32(float f) {
    unsigned int u = __float_as_uint(f);
    return (u & 0x80000000u) ? ~u : (u | 0x80000000u);
}
__device__ __forceinline__ float dec_f32(unsigned int u) {
    unsigned int v = (u & 0x80000000u) ? (u & 0x7fffffffu) : ~u;
    return __uint_as_float(v);
}

__global__ void k_init(unsigned int* scratch) {
    int t = threadIdx.x;
    if (t < B_) { scratch[t] = 0xFFFFFFFFu; scratch[B_ + t] = 0u; }
}

// K1 v2: pure streaming per-sample min/max over NHWC x (no transpose).
__global__ __launch_bounds__(256) void k_minmax(
        const float* __restrict__ x, unsigned int* __restrict__ scratch) {
    __shared__ float rmin[4], rmax[4];
    int t = threadIdx.x;
    int b = blockIdx.y;
    const float4* p = (const float4*)(x + (size_t)b * HW_ * C_);
    const int n4 = HW_ * C_ / 4;   // 401408
    float vmin = 1e30f, vmax = -1e30f;
    for (int i = blockIdx.x * 256 + t; i < n4; i += gridDim.x * 256) {
        float4 v = p[i];
        vmin = fminf(vmin, fminf(fminf(v.x, v.y), fminf(v.z, v.w)));
        vmax = fmaxf(vmax, fmaxf(fmaxf(v.x, v.y), fmaxf(v.z, v.w)));
    }
    for (int off = 32; off; off >>= 1) {
        vmin = fminf(vmin, __shfl_down(vmin, off));
        vmax = fmaxf(vmax, __shfl_down(vmax, off));
    }
    if ((t & 63) == 0) { rmin[t >> 6] = vmin; rmax[t >> 6] = vmax; }
    __syncthreads();
    if (t == 0) {
        atomicMin(&scratch[b],      enc_f32(fminf(fminf(rmin[0], rmin[1]), fminf(rmin[2], rmin[3]))));
        atomicMax(&scratch[B_ + b], enc_f32(fmaxf(fmaxf(rmax[0], rmax[1]), fmaxf(rmax[2], rmax[3]))));
    }
}

// K2 v8: v7's 512-block / 28-row-chunk decomposition with the R5/R6-proven
// compile contract __launch_bounds__(1024, 4).
// R7 lesson: (1024,8) forced VGPR from 64 -> 32; the 46-float state spilled
// (FETCH 1.1GB, WRITE 878MB of scratch, VALUBusy 6.7%, 483us). The 2nd
// launch_bounds arg is only the compiler's floor -- runtime residency is
// gated by ACTUAL usage: at VGPR=64 (natural allocation for this body, R5/
// R6) and LDS 63KB, HW co-schedules 2 blocks/CU (64 VGPR -> 8 waves/SIMD;
// 2x63KB = 126KB <= 160KB). So: grid 512 = 2/CU co-resident, one block's
// compute overlaps the other's barrier drain, WITHOUT squeezing registers.
// Ring phases are it-relative (h0 never enters slot math) -> h0=28k safe;
// 44 steps = 5x4 epochs + explicit 2-epoch tail keeps &7/&3 literal.
// XCD write pairing: bid/bid+256 (256%8==0 -> same XCD for line halves).
__global__ __launch_bounds__(1024, 4) void k_fused(
        const float* __restrict__ x, float* __restrict__ out,
        const float* __restrict__ gamma, const float* __restrict__ beta,
        const float* __restrict__ mmean, const float* __restrict__ mvar,
        const unsigned int* __restrict__ scratch) {
    __shared__ float lin[4][16][130];
    __shared__ float lout[4][16][116];
    const int t    = threadIdx.x;
    const int wid  = t >> 6;               // 0..15: channel within group
    const int lane = t & 63;

    int bid   = blockIdx.x;                // cg*256 + ((b*8+chunk)*2+strip)
    int cg    = bid >> 8;                  // pair blocks p, p+256: same XCD
    int r     = bid & 255;
    int strip = r & 1;
    int chunk = (r >> 1) & 7;              // 0..7
    int b     = r >> 4;

    const int cbase = cg * 16;
    const int c     = cbase + wid;         // this wave's channel
    const int h0    = chunk * 28;          // 0,28,...,196
    const int sbase = strip * 112;

    // BN constants (wave-uniform)
    float sc = gamma[c] * rsqrtf(mvar[c] + 1e-3f);
    float bi = beta[c] - mmean[c] * sc;

    float mn   = dec_f32(scratch[b]);
    float mx   = dec_f32(scratch[B_ + b]);
    float inv  = 1.0f / (mx - mn + 1e-7f);
    float minv = mn * inv;

    // pipeline-lane column mapping
    int c0 = sbase - 8 + 2 * lane;
    int c1 = c0 + 1;
    bool mC = (c0 >= 0) && (c0 <= W_ - 2);
    bool laneok = (lane >= 4) && (lane <= 59);

    // loader/storer mapping: 8 threads per pixel cover a 64B half-line
    int col_l = t >> 3;                    // 0..127
    int lch   = (t & 7) * 2;               // 0,2,...,14
    int wld   = min(max(sbase - 8 + col_l, 0), W_ - 1);
    int wst   = sbase - 8 + col_l;         // valid when colok
    int cs    = col_l - 8;                 // lout col index, valid when colok
    bool colok = (col_l >= 8) && (col_l < 120);
    const float* xb = x   + (size_t)b * HW_ * C_ + cbase + lch;
    float*       ob = out + (size_t)b * HW_ * C_ + cbase + lch;

    // per-column W-direction valid counts and folded constants
    float cw2_0  = (float)(min(c0+1, W_-1) - c0 + 1);
    float cw2_1  = (float)(min(c1+1, W_-1) - c1 + 1);
    float cw4_0  = (float)(min(c0+2, W_-1) - max(c0-1, 0) + 1);
    float cw4_1  = (float)(min(c1+2, W_-1) - max(c1-1, 0) + 1);
    float cw8_0  = (float)(min(c0+4, W_-1) - max(c0-3, 0) + 1);
    float cw8_1  = (float)(min(c1+4, W_-1) - max(c1-3, 0) + 1);
    float cw16_0 = (float)(min(c0+8, W_-1) - max(c0-7, 0) + 1);
    float cw16_1 = (float)(min(c1+8, W_-1) - max(c1-7, 0) + 1);
    float e2_0  = minv * cw2_0,  e2_1  = minv * cw2_1;
    float e4_0  = minv * cw4_0,  e4_1  = minv * cw4_1;
    float e8_0  = minv * cw8_0,  e8_1  = minv * cw8_1;
    float e16_0 = minv * cw16_0, e16_1 = minv * cw16_1;
    float d2_0  = 1e-7f -  2.0f * e2_0,  d2_1  = 1e-7f -  2.0f * e2_1;
    float d4_0  = 1e-7f -  4.0f * e4_0,  d4_1  = 1e-7f -  4.0f * e4_1;
    float d8_0  = 1e-7f -  8.0f * e8_0,  d8_1  = 1e-7f -  8.0f * e8_1;
    float d16_0 = 1e-7f - 16.0f * e16_0, d16_1 = 1e-7f - 16.0f * e16_1;

    float hp0 = 0.f, hp1 = 0.f;            // Xh[a-1]
    float rB4[2][2]  = {};                 // delay-2
    float rB8[2][4]  = {};                 // delay-4
    float rB16[2][8] = {};                 // delay-8
    float acc[2][8]  = {};                 // alpha partials, slot = step & 7

#define LDROW(AR) (*(const float2*)(xb + (size_t)((min(max((AR), 0), H_-1)) * W_ + wld) * C_))

// one pipeline step: read row for step U_ from lin[U_&3], update rings,
// emit out-row into lout[U_&3]. U_ literal; IT_/A_ wave-uniform runtime.
#define STEP(U_, IT_, A_) do {                                               \
    float2 lv = *(const float2*)&lin[(U_)&3][wid][2*lane];                   \
    bool rowok = ((A_) >= 0) && ((A_) < H_);                                 \
    float x0 = (rowok && mC) ? lv.x : 0.f;                                   \
    float x1 = (rowok && mC) ? lv.y : 0.f;                                   \
    float nx0 = __shfl_down(x0, 1);                                          \
    float xh0 = x0 + x1;                                                     \
    float xh1 = x1 + nx0;                                                    \
    float g2_0 = hp0 + xh0; hp0 = xh0;                                       \
    float g2_1 = hp1 + xh1; hp1 = xh1;                                       \
    float b4n_0 = g2_0 + __shfl_down(g2_0, 1);                               \
    float b4n_1 = g2_1 + __shfl_down(g2_1, 1);                               \
    float a4_0 = rB4[0][(U_)&1] + b4n_0; rB4[0][(U_)&1] = b4n_0;             \
    float a4_1 = rB4[1][(U_)&1] + b4n_1; rB4[1][(U_)&1] = b4n_1;             \
    float b8n_0 = a4_0 + __shfl_down(a4_0, 2);                               \
    float b8n_1 = a4_1 + __shfl_down(a4_1, 2);                               \
    float a8_0 = rB8[0][(U_)&3] + b8n_0; rB8[0][(U_)&3] = b8n_0;             \
    float a8_1 = rB8[1][(U_)&3] + b8n_1; rB8[1][(U_)&3] = b8n_1;             \
    float b16n_0 = a8_0 + __shfl_down(a8_0, 4);                              \
    float b16n_1 = a8_1 + __shfl_down(a8_1, 4);                              \
    float a16_0 = rB16[0][(U_)&7] + b16n_0; rB16[0][(U_)&7] = b16n_0;        \
    float a16_1 = rB16[1][(U_)&7] + b16n_1; rB16[1][(U_)&7] = b16n_1;        \
    float g4_0  = __shfl_up(a4_1, 1);                                        \
    float g4_1  = a4_0;                                                      \
    float g8_0  = __shfl_up(a8_1, 2);                                        \
    float g8_1  = __shfl_up(a8_0, 1);                                        \
    float g16_0 = __shfl_up(a16_1, 4);                                       \
    float g16_1 = __shfl_up(a16_0, 3);                                       \
    float l1_0, l1_1, l2_0, l2_1, l3_0, l3_1, l4_0, l4_1;                    \
    if ((A_) >= 15 && (A_) <= 223) {                                         \
        l1_0 = __log2f(fmaxf(fmaf(g2_0,  inv, d2_0 ), 1e-7f));               \
        l1_1 = __log2f(fmaxf(fmaf(g2_1,  inv, d2_1 ), 1e-7f));               \
        l2_0 = __log2f(fmaxf(fmaf(g4_0,  inv, d4_0 ), 1e-7f));               \
        l2_1 = __log2f(fmaxf(fmaf(g4_1,  inv, d4_1 ), 1e-7f));               \
        l3_0 = __log2f(fmaxf(fmaf(g8_0,  inv, d8_0 ), 1e-7f));               \
        l3_1 = __log2f(fmaxf(fmaf(g8_1,  inv, d8_1 ), 1e-7f));               \
        l4_0 = __log2f(fmaxf(fmaf(g16_0, inv, d16_0), 1e-7f));               \
        l4_1 = __log2f(fmaxf(fmaf(g16_1, inv, d16_1), 1e-7f));               \
    } else {                                                                 \
        int o1 = (A_) - 1, o2 = (A_) - 2, o3 = (A_) - 4, o4 = (A_) - 8;      \
        float ch2  = (float)(min(o1+1, H_-1) - o1 + 1);                      \
        float ch4  = (float)(min(o2+2, H_-1) - max(o2-1, 0) + 1);            \
        float ch8  = (float)(min(o3+4, H_-1) - max(o3-3, 0) + 1);            \
        float ch16 = (float)(min(o4+8, H_-1) - max(o4-7, 0) + 1);            \
        l1_0 = __log2f(fmaxf(fmaf(-e2_0,  ch2,  fmaf(g2_0,  inv, 1e-7f)), 1e-7f)); \
        l1_1 = __log2f(fmaxf(fmaf(-e2_1,  ch2,  fmaf(g2_1,  inv, 1e-7f)), 1e-7f)); \
        l2_0 = __log2f(fmaxf(fmaf(-e4_0,  ch4,  fmaf(g4_0,  inv, 1e-7f)), 1e-7f)); \
        l2_1 = __log2f(fmaxf(fmaf(-e4_1,  ch4,  fmaf(g4_1,  inv, 1e-7f)), 1e-7f)); \
        l3_0 = __log2f(fmaxf(fmaf(-e8_0,  ch8,  fmaf(g8_0,  inv, 1e-7f)), 1e-7f)); \
        l3_1 = __log2f(fmaxf(fmaf(-e8_1,  ch8,  fmaf(g8_1,  inv, 1e-7f)), 1e-7f)); \
        l4_0 = __log2f(fmaxf(fmaf(-e16_0, ch16, fmaf(g16_0, inv, 1e-7f)), 1e-7f)); \
        l4_1 = __log2f(fmaxf(fmaf(-e16_1, ch16, fmaf(g16_1, inv, 1e-7f)), 1e-7f)); \
    }                                                                        \
    acc[0][(U_)&7] = -0.3f * l1_0;                                           \
    acc[1][(U_)&7] = -0.3f * l1_1;                                           \
    acc[0][((U_)+7)&7] = fmaf(-0.1f, l2_0, acc[0][((U_)+7)&7]);              \
    acc[1][((U_)+7)&7] = fmaf(-0.1f, l2_1, acc[1][((U_)+7)&7]);              \
    acc[0][((U_)+5)&7] = fmaf( 0.1f, l3_0, acc[0][((U_)+5)&7]);              \
    acc[1][((U_)+5)&7] = fmaf( 0.1f, l3_1, acc[1][((U_)+5)&7]);              \
    if ((IT_) >= 15 && (IT_) <= 42) {                                        \
        float al0 = fmaf(0.3f, l4_0, acc[0][((U_)+1)&7]);                    \
        float al1 = fmaf(0.3f, l4_1, acc[1][((U_)+1)&7]);                    \
        if (laneok) {                                                        \
            float2 ev;                                                       \
            ev.x = fmaf(sc, al0, bi);                                        \
            ev.y = fmaf(sc, al1, bi);                                        \
            *(float2*)&lout[(U_)&3][wid][2*lane - 8] = ev;                   \
        }                                                                    \
    }                                                                        \
} while (0)

// one epoch = 2 steps (IT_ even, U0_ = IT_&7 literal):
// barrier; store rows emitted last epoch; stage rows for steps IT_+2/+3;
// issue loads for IT_+4/+5; run STEP(IT_), STEP(IT_+1).
#define EPOCH(U0_, IT_) do {                                                 \
    int a_ = h0 - 7 + (IT_);                                                 \
    __syncthreads();                                                         \
    if ((IT_) >= 17 && colok) {                                              \
        int o = h0 - 17 + (IT_);                                             \
        float2 sv;                                                           \
        sv.x = lout[((U0_)+2)&3][lch][cs];                                   \
        sv.y = lout[((U0_)+2)&3][lch + 1][cs];                               \
        *(float2*)(ob + (size_t)(o * W_ + wst) * C_) = sv;                   \
    }                                                                        \
    if ((IT_) >= 16 && colok) {                                              \
        int o = h0 - 16 + (IT_);                                             \
        float2 sv;                                                           \
        sv.x = lout[((U0_)+3)&3][lch][cs];                                   \
        sv.y = lout[((U0_)+3)&3][lch + 1][cs];                               \
        *(float2*)(ob + (size_t)(o * W_ + wst) * C_) = sv;                   \
    }                                                                        \
    lin[((U0_)+2)&3][lch][col_l]     = q0.x;                                 \
    lin[((U0_)+2)&3][lch + 1][col_l] = q0.y;                                 \
    lin[((U0_)+3)&3][lch][col_l]     = q1.x;                                 \
    lin[((U0_)+3)&3][lch + 1][col_l] = q1.y;                                 \
    q0 = LDROW(a_ + 4);                                                      \
    q1 = LDROW(a_ + 5);                                                      \
    STEP((U0_),     (IT_),     a_);                                          \
    STEP((U0_) + 1, (IT_) + 1, a_ + 1);                                      \
} while (0)

    // prologue: rows for steps 0,1 into lin[0],lin[1]; q0,q1 = rows for 2,3
    float2 q0, q1;
    {
        float2 r0 = LDROW(h0 - 7);
        lin[0][lch][col_l] = r0.x; lin[0][lch + 1][col_l] = r0.y;
        float2 r1 = LDROW(h0 - 6);
        lin[1][lch][col_l] = r1.x; lin[1][lch + 1][col_l] = r1.y;
        q0 = LDROW(h0 - 5);
        q1 = LDROW(h0 - 4);
    }

    // 44 steps = 22 epochs: 5 groups of 4 epochs + explicit 2-epoch tail
    for (int g = 0; g < 5; ++g) {
        int it0 = g * 8;
        EPOCH(0, it0);
        EPOCH(2, it0 + 2);
        EPOCH(4, it0 + 4);
        EPOCH(6, it0 + 6);
    }
    EPOCH(0, 40);
    EPOCH(2, 42);

    // epilogue: row emitted at step 42 (buffer 42&3 = 2), o = h0+27
    __syncthreads();
    if (colok) {
        float2 sv;
        sv.x = lout[2][lch][cs];
        sv.y = lout[2][lch + 1][cs];
        *(float2*)(ob + (size_t)((h0 + 27) * W_ + wst) * C_) = sv;
    }
#undef EPOCH
#undef STEP
#undef LDROW
}

extern "C" void kernel_launch(void* const* d_in, const int* in_sizes, int n_in,
                              void* d_out, int out_size, void* d_ws, size_t ws_size,
                              hipStream_t stream) {
    const float* x     = (const float*)d_in[0];
    const float* gamma = (const float*)d_in[1];
    const float* beta  = (const float*)d_in[2];
    const float* mmean = (const float*)d_in[3];
    const float* mvar  = (const float*)d_in[4];
    float* out = (float*)d_out;

    unsigned int* scratch = (unsigned int*)d_ws;  // 32 uints

    k_init<<<1, 64, 0, stream>>>(scratch);
    k_minmax<<<dim3(128, B_), 256, 0, stream>>>(x, scratch);
    k_fused<<<512, 1024, 0, stream>>>(x, out, gamma, beta, mmean, mvar, scratch);
}